// Round 2
// baseline (248.711 us; speedup 1.0000x reference)
//
#include <hip/hip_runtime.h>
#include <hip/hip_fp16.h>
#include <math.h>

// FBP adjoint: out[b,i0,i1,i2] = (1/A) * sum_j lerp(x[b,j,i1,:], ix(j,i0,i2))
//   ix = 16 + (i2-16)*cos(a_j) + (i0-16)*sin(a_j); y-interp is exact (iy==i1).
//
// R2: staggered fp16-pair LDS rows. Row j, dword p (p in [0,48)) holds
//   ( half(row[p-7]), half(row[p-7+1]) ), zero-padded outside [0,33).
// One ds_read_b32 fetches BOTH bilinear corners (was 2 reads / read2).
// kp = floor(ix + 7) in [0,45] indexes the pair directly.
// Block = 384 threads (6 waves), one (b,i1) per block, NV=3 (5.8% lane waste
// vs 17.5% in R1). cos/sin packed as float2 (one b64 LDS read per j).

#define PDIM 33
#define PP   1089            // 33*33
#define AMAX 121
#define ROWW 48              // padded pair-row width (dwords)
#define PADL 7               // pair p holds row[p-7], row[p-6]
#define BLK  384
#define NV   3               // 3*384 = 1152 slots for 1089 outputs

#if defined(__has_builtin)
#if __has_builtin(__builtin_amdgcn_fractf)
#define FRACTF(x) __builtin_amdgcn_fractf(x)
#endif
#endif
#ifndef FRACTF
#define FRACTF(x) ((x) - floorf(x))
#endif

__global__ __launch_bounds__(BLK)
void fbp_adjoint_kernel(const float* __restrict__ x,
                        const float* __restrict__ angles,
                        float* __restrict__ out,
                        int B, int A, float invA)
{
    __shared__ __half2 pr[AMAX * ROWW];   // staggered fp16 pairs
    __shared__ float2  cs[AMAX];          // (cos, sin)

    const int t   = threadIdx.x;
    const int blk = blockIdx.x;           // blk = b*33 + i1
    const int b   = blk / PDIM;
    const int i1  = blk - b * PDIM;

    // cos/sin per angle (once per block)
    for (int j = t; j < A; j += BLK) {
        float a = angles[j];
        float sv, cv;
        sincosf(a, &sv, &cv);
        cs[j] = make_float2(cv, sv);
    }

    // Stage staggered fp16 pairs. Global row j: 33 contiguous floats at
    // xb + j*1089 (x[b, j, i1, k]).
    const float* xb = x + (size_t)b * (A * PP) + (size_t)i1 * PDIM;
    for (int e = t; e < AMAX * ROWW; e += BLK) {
        int j = e / ROWW;
        int p = e - j * ROWW;
        int k = p - PADL;
        const float* row = xb + j * PP;
        float lo = (k >= 0 && k < PDIM)         ? row[k]     : 0.0f;
        float hi = (k + 1 >= 0 && k + 1 < PDIM) ? row[k + 1] : 0.0f;
        pr[e] = __halves2half2(__float2half_rn(lo), __float2half_rn(hi));
    }
    __syncthreads();

    // Each thread owns outputs n = t, t+384, t+768 (<1089).
    float acc[NV];
    float u0v[NV], u2v[NV];
#pragma unroll
    for (int nn = 0; nn < NV; ++nn) {
        int n  = t + nn * BLK;
        int nc = (n < PP) ? n : (PP - 1);
        int i0 = nc / PDIM;
        int i2 = nc - i0 * PDIM;
        u0v[nn] = (float)(i0 - 16);
        u2v[nn] = (float)(i2 - 16);
        acc[nn] = 0.0f;
    }

    for (int j = 0; j < A; ++j) {
        float2 csj = cs[j];
        const float c = csj.x, s = csj.y;
        int rowbase = j * ROWW;
#pragma unroll
        for (int nn = 0; nn < NV; ++nn) {
            // ixp = ix + 7 in [0.37, 45.63]  (16 + 7 = 23 folded into inner fma)
            float ixp = fmaf(u2v[nn], c, fmaf(u0v[nn], s, 23.0f));
            int   kp  = (int)ixp;            // trunc == floor (positive)
            float w1  = FRACTF(ixp);
            float w0  = 1.0f - w1;
            __half2 h2 = pr[rowbase + kp];   // (row[k0], row[k0+1])
            float v0 = __low2float(h2);
            float v1 = __high2float(h2);
            acc[nn] = fmaf(w0, v0, fmaf(w1, v1, acc[nn]));
        }
    }

    // Store: out[b, i0, i1, i2] = out[b*35937 + i0*1089 + i1*33 + i2]
    float* outb = out + (size_t)b * (PDIM * PP) + (size_t)i1 * PDIM;
#pragma unroll
    for (int nn = 0; nn < NV; ++nn) {
        int n = t + nn * BLK;
        if (n < PP) {
            int i0 = n / PDIM;
            int i2 = n - i0 * PDIM;
            outb[(size_t)i0 * PP + i2] = acc[nn] * invA;
        }
    }
}

extern "C" void kernel_launch(void* const* d_in, const int* in_sizes, int n_in,
                              void* d_out, int out_size, void* d_ws, size_t ws_size,
                              hipStream_t stream)
{
    const float* x      = (const float*)d_in[0];
    const float* angles = (const float*)d_in[1];
    float* out          = (float*)d_out;

    const int A = in_sizes[1];                    // 121
    const int B = in_sizes[0] / (A * PP);         // 128

    dim3 grid(B * PDIM);
    dim3 block(BLK);
    fbp_adjoint_kernel<<<grid, block, 0, stream>>>(x, angles, out, B, A, 1.0f / (float)A);
}